// Round 3
// baseline (423.515 us; speedup 1.0000x reference)
//
#include <hip/hip_runtime.h>
#include <stdint.h>

#define DI __device__ __forceinline__

typedef __attribute__((ext_vector_type(8))) __bf16 bf16x8;
typedef __attribute__((ext_vector_type(8))) unsigned short u16x8;
typedef __attribute__((ext_vector_type(4))) float f32x4;
typedef unsigned short u16;

constexpr int Bb = 4, Cc = 256, Ss = 4096, HD = 64;
constexpr int ELEMS = Bb * Cc * Ss;  // 4194304

DI float bf2f(u16 h) { union { unsigned u; float f; } x; x.u = ((unsigned)h) << 16; return x.f; }
DI u16 f2bf(float f) {
  union { float f; unsigned u; } x; x.f = f;
  return (u16)((x.u + 0x7FFFu + ((x.u >> 16) & 1u)) >> 16);
}
DI bf16x8 ldfrag(const u16* p) { return __builtin_bit_cast(bf16x8, *(const u16x8*)p); }

// ---------------- fp32 -> bf16 convert ----------------
__global__ __launch_bounds__(256) void k_conv(const float* __restrict__ src, u16* __restrict__ dst, int n) {
  int i = blockIdx.x * 256 + threadIdx.x;
  if (i < n) dst[i] = f2bf(src[i]);
}

// ---------------- kernel 0: x (B,C,S) fp32 -> xt (B,S,C) bf16 ----------------
__global__ __launch_bounds__(256) void k_transpose(const float* __restrict__ x, u16* __restrict__ xt) {
  __shared__ u16 T[64][72];
  const int st = blockIdx.x, ct = blockIdx.y, b = blockIdx.z;
  const int tid = threadIdx.x;
#pragma unroll
  for (int e = 0; e < 2; e++) {
    int ss = tid + e * 256;
    int r = ss >> 3, seg = ss & 7;  // r: c-local, seg*8: s-local
    size_t base = ((size_t)(b * Cc + ct * 64 + r) << 12) + st * 64 + seg * 8;
    u16x8 t;
#pragma unroll
    for (int j = 0; j < 8; j++) t[j] = f2bf(x[base + j]);
    *(u16x8*)&T[r][seg * 8] = t;
  }
  __syncthreads();
#pragma unroll
  for (int e = 0; e < 2; e++) {
    int ss = tid + e * 256;
    int sr = ss >> 3, cseg = ss & 7;  // out row: s-local, cols: c-local
    u16x8 o;
#pragma unroll
    for (int j = 0; j < 8; j++) o[j] = T[cseg * 8 + j][sr];
    *(u16x8*)(xt + ((size_t)(b * Ss + st * 64 + sr) << 8) + ct * 64 + cseg * 8) = o;
  }
}

// ---- shared GEMM staging: rows [r0,r0+128) x cols [k0,k0+32), pitch-40 LDS ----
DI void stage_tile(const u16* __restrict__ src, int pitch, int r0, int k0, u16 (*dst)[40], int tid) {
#pragma unroll
  for (int e = 0; e < 2; e++) {
    int c = tid + e * 256;
    int row = c >> 2, seg = c & 3;
    u16x8 t = *(const u16x8*)(src + (size_t)(r0 + row) * pitch + k0 + seg * 8);
    *(u16x8*)&dst[row][seg * 8] = t;
  }
}

// ---------------- kernel 1: qkv = xt @ w_qkv^T + b, scatter to q/k/v [bh][s][64] bf16 ----------------
__global__ __launch_bounds__(256) void k_qkv(const u16* __restrict__ xt, const u16* __restrict__ w,
                                             const float* __restrict__ bias,
                                             u16* __restrict__ q, u16* __restrict__ kk_, u16* __restrict__ vv_) {
  __shared__ u16 As[128][40], Bs[128][40];
  const int tid = threadIdx.x;
  const int wv = tid >> 6, lane = tid & 63;
  const int wm = wv >> 1, wn = wv & 1;
  const int lr = lane & 15, quad = lane >> 4;
  const int r0 = blockIdx.x * 128;  // rows = b*s
  const int j0 = blockIdx.y * 128;  // cols in [0,768)
  f32x4 acc[4][4] = {};
  for (int k0 = 0; k0 < 256; k0 += 32) {
    __syncthreads();
    stage_tile(xt, 256, r0, k0, As, tid);
    stage_tile(w, 256, j0, k0, Bs, tid);
    __syncthreads();
    bf16x8 a[4], b[4];
#pragma unroll
    for (int mt = 0; mt < 4; mt++) a[mt] = ldfrag(&As[wm * 64 + mt * 16 + lr][quad * 8]);
#pragma unroll
    for (int nt = 0; nt < 4; nt++) b[nt] = ldfrag(&Bs[wn * 64 + nt * 16 + lr][quad * 8]);
#pragma unroll
    for (int mt = 0; mt < 4; mt++)
#pragma unroll
      for (int nt = 0; nt < 4; nt++)
        acc[mt][nt] = __builtin_amdgcn_mfma_f32_16x16x32_bf16(a[mt], b[nt], acc[mt][nt], 0, 0, 0);
  }
#pragma unroll
  for (int nt = 0; nt < 4; nt++) {
    int j = j0 + wn * 64 + nt * 16 + lr;
    float bj = bias[j];
    int part = j >> 8, cc = j & 255, head = cc >> 6, d = cc & 63;
    u16* outp = (part == 0) ? q : (part == 1) ? kk_ : vv_;
#pragma unroll
    for (int mt = 0; mt < 4; mt++)
#pragma unroll
      for (int rg = 0; rg < 4; rg++) {
        int row = r0 + wm * 64 + mt * 16 + quad * 4 + rg;
        int b_ = row >> 12, s = row & 4095;
        outp[((size_t)((b_ * 4 + head) * Ss + s) << 6) + d] = f2bf(acc[mt][nt][rg] + bj);
      }
  }
}

// ---------------- kernel 2: flash attention per (bh, 128-row q tile) ----------------
__global__ __launch_bounds__(256) void k_attn(const u16* __restrict__ Q, const u16* __restrict__ K,
                                              const u16* __restrict__ V, u16* __restrict__ AO) {
  __shared__ u16 Kl[64][72];
  __shared__ u16 Vt[64][72];
  __shared__ u16 Pl[128][72];
  const int tid = threadIdx.x;
  const int wv = tid >> 6, lane = tid & 63;
  const int lr = lane & 15, quad = lane >> 4;
  const int bh = blockIdx.y;
  const int b_ = bh >> 2, head = bh & 3;
  const int q0 = blockIdx.x * 128;
  const u16* Qh = Q + (size_t)bh * Ss * HD;
  const u16* Kh = K + (size_t)bh * Ss * HD;
  const u16* Vh = V + (size_t)bh * Ss * HD;

  bf16x8 qf[2][2];
#pragma unroll
  for (int mt = 0; mt < 2; mt++)
#pragma unroll
    for (int ks = 0; ks < 2; ks++)
      qf[mt][ks] = ldfrag(Qh + (size_t)(q0 + wv * 32 + mt * 16 + lr) * HD + ks * 32 + quad * 8);

  f32x4 O[2][4] = {};
  float mrow[2][4], lrow[2][4];
#pragma unroll
  for (int mt = 0; mt < 2; mt++)
#pragma unroll
    for (int rg = 0; rg < 4; rg++) { mrow[mt][rg] = -1e30f; lrow[mt][rg] = 0.f; }
  const float scale = 0.125f;

  for (int kc = 0; kc < 64; kc++) {
    __syncthreads();
    // stage K chunk [64 keys][64 d] -> Kl (pitch 72)
#pragma unroll
    for (int e = 0; e < 2; e++) {
      int ss = tid + e * 256;
      int row = ss >> 3, seg = ss & 7;
      u16x8 t = *(const u16x8*)(Kh + ((size_t)(kc * 64 + row) << 6) + seg * 8);
      *(u16x8*)&Kl[row][seg * 8] = t;
    }
    // stage V chunk transposed -> Vt[d][key]
#pragma unroll
    for (int e = 0; e < 2; e++) {
      int ss = tid + e * 256;
      int key = ss >> 3, db = (ss & 7) * 8;
      u16x8 t = *(const u16x8*)(Vh + ((size_t)(kc * 64 + key) << 6) + db);
#pragma unroll
      for (int j = 0; j < 8; j++) Vt[db + j][key] = t[j];
    }
    __syncthreads();

    // S = Q K^T  (rows: q, cols: key-in-chunk)
    f32x4 Sf[2][4] = {};
#pragma unroll
    for (int ks = 0; ks < 2; ks++) {
      bf16x8 bfr[4];
#pragma unroll
      for (int nt = 0; nt < 4; nt++) bfr[nt] = ldfrag(&Kl[nt * 16 + lr][ks * 32 + quad * 8]);
#pragma unroll
      for (int mt = 0; mt < 2; mt++)
#pragma unroll
        for (int nt = 0; nt < 4; nt++)
          Sf[mt][nt] = __builtin_amdgcn_mfma_f32_16x16x32_bf16(qf[mt][ks], bfr[nt], Sf[mt][nt], 0, 0, 0);
    }

    // online softmax; write P (bf16) to LDS in A-operand-friendly row-major
#pragma unroll
    for (int mt = 0; mt < 2; mt++) {
      float corr[4], psum[4];
#pragma unroll
      for (int rg = 0; rg < 4; rg++) {
        float m0 = fmaxf(fmaxf(Sf[mt][0][rg], Sf[mt][1][rg]), fmaxf(Sf[mt][2][rg], Sf[mt][3][rg]));
#pragma unroll
        for (int off = 1; off < 16; off <<= 1) m0 = fmaxf(m0, __shfl_xor(m0, off));
        float mn = fmaxf(mrow[mt][rg], m0 * scale);
        corr[rg] = __expf(mrow[mt][rg] - mn);
        mrow[mt][rg] = mn;
        psum[rg] = 0.f;
      }
#pragma unroll
      for (int nt = 0; nt < 4; nt++)
#pragma unroll
        for (int rg = 0; rg < 4; rg++) {
          float p = __expf(Sf[mt][nt][rg] * scale - mrow[mt][rg]);
          psum[rg] += p;
          Pl[wv * 32 + mt * 16 + quad * 4 + rg][nt * 16 + lr] = f2bf(p);
        }
#pragma unroll
      for (int rg = 0; rg < 4; rg++) {
#pragma unroll
        for (int off = 1; off < 16; off <<= 1) psum[rg] += __shfl_xor(psum[rg], off);
        lrow[mt][rg] = lrow[mt][rg] * corr[rg] + psum[rg];
      }
#pragma unroll
      for (int dt = 0; dt < 4; dt++)
#pragma unroll
        for (int rg = 0; rg < 4; rg++) O[mt][dt][rg] *= corr[rg];
    }

    __syncthreads();  // P writes visible before P reads (strictly safe)

    // O += P V
    bf16x8 af[2][2];
#pragma unroll
    for (int mt = 0; mt < 2; mt++)
#pragma unroll
      for (int ks = 0; ks < 2; ks++)
        af[mt][ks] = ldfrag(&Pl[wv * 32 + mt * 16 + lr][ks * 32 + quad * 8]);
#pragma unroll
    for (int dt = 0; dt < 4; dt++)
#pragma unroll
      for (int ks = 0; ks < 2; ks++) {
        bf16x8 bfr = ldfrag(&Vt[dt * 16 + lr][ks * 32 + quad * 8]);
#pragma unroll
        for (int mt = 0; mt < 2; mt++)
          O[mt][dt] = __builtin_amdgcn_mfma_f32_16x16x32_bf16(af[mt][ks], bfr, O[mt][dt], 0, 0, 0);
      }
  }

  // epilogue: divide by l, write ao[b][s][head*64+d] (bf16)
#pragma unroll
  for (int mt = 0; mt < 2; mt++)
#pragma unroll
    for (int rg = 0; rg < 4; rg++) {
      float inv = 1.0f / lrow[mt][rg];
      int s = q0 + wv * 32 + mt * 16 + quad * 4 + rg;
#pragma unroll
      for (int dt = 0; dt < 4; dt++)
        AO[((size_t)(b_ * Ss + s) << 8) + head * 64 + dt * 16 + lr] = f2bf(O[mt][dt][rg] * inv);
    }
}

// ---------------- kernel 3: y^T = w_o * ao^T + b_o, stored as y[b][c][s] FP32 ----------------
__global__ __launch_bounds__(256) void k_oproj(const u16* __restrict__ wo, const u16* __restrict__ ao,
                                               const float* __restrict__ bo, float* __restrict__ y) {
  __shared__ u16 As[128][40], Bs[128][40];
  const int tid = threadIdx.x;
  const int wv = tid >> 6, lane = tid & 63;
  const int wm = wv >> 1, wn = wv & 1;
  const int lr = lane & 15, quad = lane >> 4;
  const int c0 = blockIdx.x * 128;  // rows = out channel (256)
  const int n0 = blockIdx.y * 128;  // cols = b*s (16384)
  f32x4 acc[4][4] = {};
  for (int k0 = 0; k0 < 256; k0 += 32) {
    __syncthreads();
    stage_tile(wo, 256, c0, k0, As, tid);
    stage_tile(ao, 256, n0, k0, Bs, tid);
    __syncthreads();
    bf16x8 a[4], b[4];
#pragma unroll
    for (int mt = 0; mt < 4; mt++) a[mt] = ldfrag(&As[wm * 64 + mt * 16 + lr][quad * 8]);
#pragma unroll
    for (int nt = 0; nt < 4; nt++) b[nt] = ldfrag(&Bs[wn * 64 + nt * 16 + lr][quad * 8]);
#pragma unroll
    for (int mt = 0; mt < 4; mt++)
#pragma unroll
      for (int nt = 0; nt < 4; nt++)
        acc[mt][nt] = __builtin_amdgcn_mfma_f32_16x16x32_bf16(a[mt], b[nt], acc[mt][nt], 0, 0, 0);
  }
#pragma unroll
  for (int mt = 0; mt < 4; mt++)
#pragma unroll
    for (int rg = 0; rg < 4; rg++) {
      int c = c0 + wm * 64 + mt * 16 + quad * 4 + rg;
      float bc = bo[c];
#pragma unroll
      for (int nt = 0; nt < 4; nt++) {
        int col = n0 + wn * 64 + nt * 16 + lr;
        int b_ = col >> 12, s = col & 4095;
        y[((size_t)(b_ * Cc + c) << 12) + s] = acc[mt][nt][rg] + bc;
      }
    }
}

extern "C" void kernel_launch(void* const* d_in, const int* in_sizes, int n_in,
                              void* d_out, int out_size, void* d_ws, size_t ws_size,
                              hipStream_t stream) {
  const float* x = (const float*)d_in[0];
  const float* w_qkv = (const float*)d_in[1];
  const float* b_qkv = (const float*)d_in[2];
  const float* w_o = (const float*)d_in[3];
  const float* b_o = (const float*)d_in[4];
  float* y = (float*)d_out;
  u16* ws = (u16*)d_ws;
  u16* xt = ws;                        // [0, E)  — reused as ao after k_qkv
  u16* q = ws + (size_t)ELEMS;         // [E, 2E)
  u16* k = ws + (size_t)2 * ELEMS;     // [2E, 3E)
  u16* v = ws + (size_t)3 * ELEMS;     // [3E, 4E)
  u16* ao = xt;                        // alias: xt dead after k_qkv
  u16* wqb = ws + (size_t)4 * ELEMS;   // 196608
  u16* wob = wqb + 196608;             // 65536

  k_conv<<<768, 256, 0, stream>>>(w_qkv, wqb, 196608);
  k_conv<<<256, 256, 0, stream>>>(w_o, wob, 65536);
  k_transpose<<<dim3(64, 4, 4), 256, 0, stream>>>(x, xt);
  k_qkv<<<dim3(128, 6), 256, 0, stream>>>(xt, wqb, b_qkv, q, k, v);
  k_attn<<<dim3(32, 16), 256, 0, stream>>>(q, k, v, ao);
  k_oproj<<<dim3(2, 128), 256, 0, stream>>>(wob, ao, b_o, y);
}

// Round 4
// 216.987 us; speedup vs baseline: 1.9518x; 1.9518x over previous
//
#include <hip/hip_runtime.h>
#include <stdint.h>

#define DI __device__ __forceinline__

typedef __attribute__((ext_vector_type(8))) __bf16 bf16x8;
typedef __attribute__((ext_vector_type(8))) unsigned short u16x8;
typedef __attribute__((ext_vector_type(4))) float f32x4;
typedef unsigned short u16;

constexpr int Bb = 4, Cc = 256, Ss = 4096, HD = 64;
constexpr int ELEMS = Bb * Cc * Ss;  // 4194304

DI u16 f2bf(float f) {  // RNE
  union { float f; unsigned u; } x; x.f = f;
  return (u16)((x.u + 0x7FFFu + ((x.u >> 16) & 1u)) >> 16);
}
DI uint32_t pack2bf(float a, float b) {  // low16=bf(a), high16=bf(b), round-half-up
  union { float f; uint32_t u; } xa, xb;
  xa.f = a; xb.f = b;
  return __builtin_amdgcn_perm(xb.u + 0x8000u, xa.u + 0x8000u, 0x07060302u);
}
DI bf16x8 ldfrag(const u16* p) { return __builtin_bit_cast(bf16x8, *(const u16x8*)p); }

// ---------------- fp32 -> bf16 convert ----------------
__global__ __launch_bounds__(256) void k_conv(const float* __restrict__ src, u16* __restrict__ dst, int n) {
  int i = blockIdx.x * 256 + threadIdx.x;
  if (i < n) dst[i] = f2bf(src[i]);
}

// ---------------- kernel 0: x (B,C,S) fp32 -> xt (B,S,C) bf16 ----------------
__global__ __launch_bounds__(256) void k_transpose(const float* __restrict__ x, u16* __restrict__ xt) {
  __shared__ u16 T[64][72];
  const int st = blockIdx.x, ct = blockIdx.y, b = blockIdx.z;
  const int tid = threadIdx.x;
#pragma unroll
  for (int e = 0; e < 2; e++) {
    int ss = tid + e * 256;
    int r = ss >> 3, seg = ss & 7;
    size_t base = ((size_t)(b * Cc + ct * 64 + r) << 12) + st * 64 + seg * 8;
    u16x8 t;
#pragma unroll
    for (int j = 0; j < 8; j++) t[j] = f2bf(x[base + j]);
    *(u16x8*)&T[r][seg * 8] = t;
  }
  __syncthreads();
#pragma unroll
  for (int e = 0; e < 2; e++) {
    int ss = tid + e * 256;
    int sr = ss >> 3, cseg = ss & 7;
    u16x8 o;
#pragma unroll
    for (int j = 0; j < 8; j++) o[j] = T[cseg * 8 + j][sr];
    *(u16x8*)(xt + ((size_t)(b * Ss + st * 64 + sr) << 8) + ct * 64 + cseg * 8) = o;
  }
}

// ---- shared GEMM staging: rows [r0,r0+128) x cols [k0,k0+32), pitch-40 LDS ----
DI void stage_tile(const u16* __restrict__ src, int pitch, int r0, int k0, u16 (*dst)[40], int tid) {
#pragma unroll
  for (int e = 0; e < 2; e++) {
    int c = tid + e * 256;
    int row = c >> 2, seg = c & 3;
    u16x8 t = *(const u16x8*)(src + (size_t)(r0 + row) * pitch + k0 + seg * 8);
    *(u16x8*)&dst[row][seg * 8] = t;
  }
}

// ---------------- kernel 1: qkv GEMM.  q:[bh][s][64]*0.125  k:[bh][s][64]  v:[bh][64][perm(s)] ----------------
__global__ __launch_bounds__(256) void k_qkv(const u16* __restrict__ xt, const u16* __restrict__ w,
                                             const float* __restrict__ bias,
                                             u16* __restrict__ q, u16* __restrict__ kk_, u16* __restrict__ vt_) {
  __shared__ u16 As[128][40], Bs[128][40];
  const int tid = threadIdx.x;
  const int wv = tid >> 6, lane = tid & 63;
  const int wm = wv >> 1, wn = wv & 1;
  const int lr = lane & 15, quad = lane >> 4;
  const int r0 = blockIdx.x * 128;  // rows = b*s
  const int j0 = blockIdx.y * 128;  // cols in [0,768)
  f32x4 acc[4][4] = {};
  for (int k0 = 0; k0 < 256; k0 += 32) {
    __syncthreads();
    stage_tile(xt, 256, r0, k0, As, tid);
    stage_tile(w, 256, j0, k0, Bs, tid);
    __syncthreads();
    bf16x8 a[4], b[4];
#pragma unroll
    for (int mt = 0; mt < 4; mt++) a[mt] = ldfrag(&As[wm * 64 + mt * 16 + lr][quad * 8]);
#pragma unroll
    for (int nt = 0; nt < 4; nt++) b[nt] = ldfrag(&Bs[wn * 64 + nt * 16 + lr][quad * 8]);
#pragma unroll
    for (int mt = 0; mt < 4; mt++)
#pragma unroll
      for (int nt = 0; nt < 4; nt++)
        acc[mt][nt] = __builtin_amdgcn_mfma_f32_16x16x32_bf16(a[mt], b[nt], acc[mt][nt], 0, 0, 0);
  }
#pragma unroll
  for (int nt = 0; nt < 4; nt++) {
    int j = j0 + wn * 64 + nt * 16 + lr;
    float bj = bias[j];
    int part = j >> 8, cc = j & 255, head = cc >> 6, d = cc & 63;
#pragma unroll
    for (int mt = 0; mt < 4; mt++)
#pragma unroll
      for (int rg = 0; rg < 4; rg++) {
        int row = r0 + wm * 64 + mt * 16 + quad * 4 + rg;
        int b_ = row >> 12, s = row & 4095;
        float val = acc[mt][nt][rg] + bj;
        if (part == 0) {
          q[((size_t)((b_ * 4 + head) * Ss + s) << 6) + d] = f2bf(val * 0.125f);
        } else if (part == 1) {
          kk_[((size_t)((b_ * 4 + head) * Ss + s) << 6) + d] = f2bf(val);
        } else {
          // permuted-transposed V: vt[bh][d][chunk*64 + slot], slot = 32*(t>>1)+8*qq+4*(t&1)+r
          int chunk = s >> 6, w6 = s & 63;
          int t = w6 >> 4, qq = (w6 >> 2) & 3, r = w6 & 3;
          int slot = ((t >> 1) << 5) | (qq << 3) | ((t & 1) << 2) | r;
          vt_[((size_t)((b_ * 4 + head) * 64 + d) << 12) + chunk * 64 + slot] = f2bf(val);
        }
      }
  }
}

// ---------------- kernel 2: flash attention, S^T formulation, no-max softmax ----------------
// per block: 128 q-rows (4 waves x 32), loop over 64-key chunks.
// S^T = K·Q^T lands so that exp(S^T) packed in-lane IS the PV A-operand (permuted key order,
// matched by the permuted V layout). No P round-trip, no cross-lane moves in the hot loop.
__global__ __launch_bounds__(256) void k_attn(const u16* __restrict__ Q, const u16* __restrict__ K,
                                              const u16* __restrict__ VT, u16* __restrict__ AO) {
  __shared__ u16 Kl[64][72];
  __shared__ u16 Vl[64][72];
  const int tid = threadIdx.x;
  const int wv = tid >> 6, lane = tid & 63;
  const int lr = lane & 15, quad = lane >> 4;
  const int bh = blockIdx.y;
  const int b_ = bh >> 2, head = bh & 3;
  const int qbase = blockIdx.x * 128 + wv * 32;
  const u16* Qh = Q + (size_t)bh * Ss * HD;
  const u16* Kh = K + (size_t)bh * Ss * HD;
  const u16* Vh = VT + (size_t)bh * HD * Ss;  // [d][perm(s)]

  // Q as B-operand (Q pre-scaled by 0.125 in k_qkv): qb[nt][ks]
  bf16x8 qb[2][2];
#pragma unroll
  for (int nt = 0; nt < 2; nt++)
#pragma unroll
    for (int ks = 0; ks < 2; ks++)
      qb[nt][ks] = ldfrag(Qh + (size_t)(qbase + nt * 16 + lr) * HD + ks * 32 + quad * 8);

  f32x4 O[2][4] = {};
  float lsum[2] = {0.f, 0.f};

  for (int kc = 0; kc < 64; kc++) {
    __syncthreads();
#pragma unroll
    for (int e = 0; e < 2; e++) {
      int ss = tid + e * 256;
      int row = ss >> 3, seg = ss & 7;
      *(u16x8*)&Kl[row][seg * 8] = *(const u16x8*)(Kh + ((size_t)(kc * 64 + row) << 6) + seg * 8);
      *(u16x8*)&Vl[row][seg * 8] = *(const u16x8*)(Vh + ((size_t)row << 12) + kc * 64 + seg * 8);
    }
    __syncthreads();

    // S^T[key][q] = K·Q^T ; frag St[kt][nt]: lane holds key=kt*16+quad*4+rg, q=nt*16+lr
    f32x4 St[4][2] = {};
#pragma unroll
    for (int ks = 0; ks < 2; ks++) {
      bf16x8 ka[4];
#pragma unroll
      for (int kt = 0; kt < 4; kt++) ka[kt] = ldfrag(&Kl[kt * 16 + lr][ks * 32 + quad * 8]);
#pragma unroll
      for (int kt = 0; kt < 4; kt++)
#pragma unroll
        for (int nt = 0; nt < 2; nt++)
          St[kt][nt] = __builtin_amdgcn_mfma_f32_16x16x32_bf16(ka[kt], qb[nt][ks], St[kt][nt], 0, 0, 0);
    }

    // p = exp(score); accumulate per-lane l partials; pack to bf16 dwords in-register
    uint32_t pk[4][2][2];
#pragma unroll
    for (int kt = 0; kt < 4; kt++)
#pragma unroll
      for (int nt = 0; nt < 2; nt++) {
        float p0 = __expf(St[kt][nt][0]);
        float p1 = __expf(St[kt][nt][1]);
        float p2 = __expf(St[kt][nt][2]);
        float p3 = __expf(St[kt][nt][3]);
        lsum[nt] += (p0 + p1) + (p2 + p3);
        pk[kt][nt][0] = pack2bf(p0, p1);
        pk[kt][nt][1] = pack2bf(p2, p3);
      }

    // O += P·V : A-frag is the lane's own packed registers (key-permuted order);
    // V B-frags read contiguous (same permuted order baked into global VT layout).
#pragma unroll
    for (int ks = 0; ks < 2; ks++) {
      bf16x8 pa[2];
#pragma unroll
      for (int mt = 0; mt < 2; mt++) {
        union { bf16x8 v; uint32_t d[4]; } u;
        u.d[0] = pk[2 * ks][mt][0];
        u.d[1] = pk[2 * ks][mt][1];
        u.d[2] = pk[2 * ks + 1][mt][0];
        u.d[3] = pk[2 * ks + 1][mt][1];
        pa[mt] = u.v;
      }
#pragma unroll
      for (int dt = 0; dt < 4; dt++) {
        bf16x8 vb = ldfrag(&Vl[dt * 16 + lr][ks * 32 + quad * 8]);
#pragma unroll
        for (int mt = 0; mt < 2; mt++)
          O[mt][dt] = __builtin_amdgcn_mfma_f32_16x16x32_bf16(pa[mt], vb, O[mt][dt], 0, 0, 0);
      }
    }
  }

  // finalize l: reduce across the 4 quads holding the same q-column
#pragma unroll
  for (int nt = 0; nt < 2; nt++) {
    lsum[nt] += __shfl_xor(lsum[nt], 16);
    lsum[nt] += __shfl_xor(lsum[nt], 32);
  }
  // epilogue: O rows are quad*4+rg; fetch l from lane (quad*4+rg), divide, store
#pragma unroll
  for (int mt = 0; mt < 2; mt++)
#pragma unroll
    for (int rg = 0; rg < 4; rg++) {
      float lv = __shfl(lsum[mt], quad * 4 + rg);
      float inv = 1.0f / lv;
      int s = qbase + mt * 16 + quad * 4 + rg;
#pragma unroll
      for (int dt = 0; dt < 4; dt++)
        AO[((size_t)(b_ * Ss + s) << 8) + head * 64 + dt * 16 + lr] = f2bf(O[mt][dt][rg] * inv);
    }
}

// ---------------- kernel 3: y^T = w_o * ao^T + b_o, stored as y[b][c][s] FP32 ----------------
__global__ __launch_bounds__(256) void k_oproj(const u16* __restrict__ wo, const u16* __restrict__ ao,
                                               const float* __restrict__ bo, float* __restrict__ y) {
  __shared__ u16 As[128][40], Bs[128][40];
  const int tid = threadIdx.x;
  const int wv = tid >> 6, lane = tid & 63;
  const int wm = wv >> 1, wn = wv & 1;
  const int lr = lane & 15, quad = lane >> 4;
  const int c0 = blockIdx.x * 128;
  const int n0 = blockIdx.y * 128;
  f32x4 acc[4][4] = {};
  for (int k0 = 0; k0 < 256; k0 += 32) {
    __syncthreads();
    stage_tile(wo, 256, c0, k0, As, tid);
    stage_tile(ao, 256, n0, k0, Bs, tid);
    __syncthreads();
    bf16x8 a[4], b[4];
#pragma unroll
    for (int mt = 0; mt < 4; mt++) a[mt] = ldfrag(&As[wm * 64 + mt * 16 + lr][quad * 8]);
#pragma unroll
    for (int nt = 0; nt < 4; nt++) b[nt] = ldfrag(&Bs[wn * 64 + nt * 16 + lr][quad * 8]);
#pragma unroll
    for (int mt = 0; mt < 4; mt++)
#pragma unroll
      for (int nt = 0; nt < 4; nt++)
        acc[mt][nt] = __builtin_amdgcn_mfma_f32_16x16x32_bf16(a[mt], b[nt], acc[mt][nt], 0, 0, 0);
  }
#pragma unroll
  for (int mt = 0; mt < 4; mt++)
#pragma unroll
    for (int rg = 0; rg < 4; rg++) {
      int c = c0 + wm * 64 + mt * 16 + quad * 4 + rg;
      float bc = bo[c];
#pragma unroll
      for (int nt = 0; nt < 4; nt++) {
        int col = n0 + wn * 64 + nt * 16 + lr;
        int b_ = col >> 12, s = col & 4095;
        y[((size_t)(b_ * Cc + c) << 12) + s] = acc[mt][nt][rg] + bc;
      }
    }
}

extern "C" void kernel_launch(void* const* d_in, const int* in_sizes, int n_in,
                              void* d_out, int out_size, void* d_ws, size_t ws_size,
                              hipStream_t stream) {
  const float* x = (const float*)d_in[0];
  const float* w_qkv = (const float*)d_in[1];
  const float* b_qkv = (const float*)d_in[2];
  const float* w_o = (const float*)d_in[3];
  const float* b_o = (const float*)d_in[4];
  float* y = (float*)d_out;
  u16* ws = (u16*)d_ws;
  u16* xt = ws;                        // [0, E) — reused as ao after k_qkv
  u16* q = ws + (size_t)ELEMS;         // [E, 2E)
  u16* k = ws + (size_t)2 * ELEMS;     // [2E, 3E)
  u16* vt = ws + (size_t)3 * ELEMS;    // [3E, 4E)  — transposed+permuted V
  u16* ao = xt;                        // alias: xt dead after k_qkv
  u16* wqb = ws + (size_t)4 * ELEMS;   // 196608
  u16* wob = wqb + 196608;             // 65536

  k_conv<<<768, 256, 0, stream>>>(w_qkv, wqb, 196608);
  k_conv<<<256, 256, 0, stream>>>(w_o, wob, 65536);
  k_transpose<<<dim3(64, 4, 4), 256, 0, stream>>>(x, xt);
  k_qkv<<<dim3(128, 6), 256, 0, stream>>>(xt, wqb, b_qkv, q, k, vt);
  k_attn<<<dim3(32, 16), 256, 0, stream>>>(q, k, vt, ao);
  k_oproj<<<dim3(2, 128), 256, 0, stream>>>(wob, ao, b_o, y);
}